// Round 1
// 210.950 us; speedup vs baseline: 1.0716x; 1.0716x over previous
//
#include <hip/hip_runtime.h>

// out[r*64+ch] = b[ch] + sum_{edges (r,c)} W[ch][c],  r normalized by row.min().
// N = 100000, C = 64, E = 3.2M.
//
// R12: bgather rebuilt as issue-bound fix (R11 counters: 31% HBM, 48% VALU,
//  53% occ => instruction-issue bound, NOT latency*concurrency as R10 thought;
//  Little's law gives 1.7us effective per load slot = slots starved).
//  - dword gather: Wtb read as uint, lane l of each 32-lane half covers
//    channels 2l/2l+1; halves process even/odd records => load instrs and
//    addr VALU halved per record. One shfl_xor(32) per ROW merges halves.
//  - col indices via ds_read_b128/b64 (2-4 lgkm ops per 16 records vs 16).
//    Rows padded to even cnt with sentinel col N; Wtb row N is zeros.
//  - 2 sub-blocks x 128 rows, 512 thr, 32KB LDS => 4 blocks/CU, 32 waves/CU
//    (100% occ), 782-block grid fully resident; recs scanned 2x not 4x.
//  Lessons kept: no shfl-broadcast-per-record accum (R3/R7 ~1410us twice);
//  no same-line global atomics (R5); independent gather loads (R6/R9).
// ws: flags | Wtb[(N+1)*64 bf16] | gtail[nbkt*16] | ovf | recs[nbkt*segcap]

#define OVF_MAX (1 << 19)
#define NBKT_MAX 400
#define SLOTS 36
#define FLUSH_T 24
#define GT_STRIDE 16
#define SL 64           // LDS col-list slots per row

__device__ __forceinline__ float bf16u_to_f(unsigned short u) {
    union { unsigned int i; float f; } x; x.i = ((unsigned int)u) << 16; return x.f;
}
__device__ __forceinline__ float bflo(unsigned int u) {
    union { unsigned int i; float f; } x; x.i = u << 16; return x.f;
}
__device__ __forceinline__ float bfhi(unsigned int u) {
    union { unsigned int i; float f; } x; x.i = u & 0xFFFF0000u; return x.f;
}

// 1 block: dtype probe (head+tail odd words) + flags/gtail init.
__global__ __launch_bounds__(1024) void LINK_detect_kernel(
    const unsigned int* __restrict__ words, int E, int* __restrict__ flags,
    int* __restrict__ gtail, int nbkt, int segcap) {
    long long twoE = 2LL * E;
    int tid = threadIdx.x;
    unsigned int oddOr = 0u;
    int nscan = (int)(twoE < 8192 ? twoE : 8192);
    for (int i = tid; i < nscan; i += blockDim.x) {
        if (i & 1) oddOr |= words[i];
        long long j = twoE - 1 - i;
        if (j >= nscan && (j & 1)) oddOr |= words[j];
    }
    __shared__ unsigned int sred[16];
    for (int off = 32; off > 0; off >>= 1)
        oddOr |= (unsigned int)__shfl_down((int)oddOr, off, 64);
    int wid = tid >> 6;
    if ((tid & 63) == 0) sred[wid] = oddOr;
    __syncthreads();
    if (tid == 0) {
        unsigned int o = 0;
        for (int i = 0; i < (int)(blockDim.x >> 6); ++i) o |= sred[i];
        flags[0] = o ? 1 : 0;   // 1 = int32 layout
        flags[1] = 0x7fffffff;  // rmin (partition fills via atomicMin)
        flags[8] = 0;           // ovf count
    }
    for (int k = tid; k < nbkt; k += blockDim.x) gtail[k * GT_STRIDE] = k * segcap;
}

// W [64][N] f32 -> Wtb [N+1][64] bf16 (RNE) via padded LDS tile. Row N = zeros
// (gather sentinel for odd-count padding).
__global__ void LINK_transpose_kernel(const float* __restrict__ W,
                                      unsigned short* __restrict__ Wtb, int N) {
    __shared__ float tile[64][65];
    int n0 = blockIdx.x * 64;
    int lx = threadIdx.x & 63;
    int ly = threadIdx.x >> 6;
#pragma unroll
    for (int it = 0; it < 16; ++it) {
        int ch = ly + 4 * it;
        float v = 0.0f;
        if (n0 + lx < N) v = W[(size_t)ch * N + (n0 + lx)];
        tile[lx][ch] = v;
    }
    __syncthreads();
#pragma unroll
    for (int it = 0; it < 16; ++it) {
        int nn = ly + 4 * it;
        if (n0 + nn <= N) {   // row N gets zeros (load guard) -> sentinel row
            union { float f; unsigned int i; } x; x.f = tile[nn][lx];
            unsigned int u = x.i;
            unsigned int r = (u + 0x7fffu + ((u >> 16) & 1u)) >> 16;  // RNE
            Wtb[((size_t)(n0 + nn) << 6) + lx] = (unsigned short)r;
        }
    }
}

// Edges -> 256-row buckets. Records 4B: (r&255)<<17 | c. LDS-staged, wave-wide
// coalesced flushes. Also block-reduces rmin -> atomicMin(flags[1]).
__global__ __launch_bounds__(1024) void LINK_part_kernel(
    const unsigned int* __restrict__ words, int E, int N, int nbkt, int segcap,
    int* __restrict__ gtail, unsigned int* __restrict__ recs,
    int* __restrict__ ovf, int* __restrict__ flags) {
    __shared__ unsigned int lstage[NBKT_MAX * SLOTS];  // 57.6 KB
    __shared__ int lcnt[NBKT_MAX];
    __shared__ int sred[16];
    int tid = threadIdx.x;
    for (int k = tid; k < nbkt; k += blockDim.x) lcnt[k] = 0;
    __syncthreads();
    int isInt32 = flags[0];
    int mnr = 0x7fffffff;
    int nblk = gridDim.x;
    long long per_round = (long long)nblk * blockDim.x;
    long long nround = ((long long)E + per_round - 1) / per_round;
    int lane = tid & 63, wid = tid >> 6, nw = blockDim.x >> 6;
    for (long long rd = 0; rd < nround; ++rd) {
        long long e = (rd * nblk + blockIdx.x) * blockDim.x + tid;
        if (e < E) {
            int r, c;
            if (isInt32) {
                r = (int)__builtin_nontemporal_load(words + e);
                c = (int)__builtin_nontemporal_load(words + E + e);
            } else {
                r = (int)__builtin_nontemporal_load(words + 2 * e);
                c = (int)__builtin_nontemporal_load(words + 2LL * E + 2 * e);
            }
            mnr = min(mnr, r);
            if ((unsigned)r < (unsigned)N && (unsigned)c < (unsigned)N) {
                int k = r >> 8;
                unsigned int rec = ((unsigned int)(r & 255) << 17) | (unsigned int)c;
                int pos = atomicAdd(&lcnt[k], 1);
                if (pos < SLOTS) {
                    lstage[k * SLOTS + pos] = rec;
                } else {  // rare mid-round spill: direct global append
                    int g = atomicAdd(&gtail[k * GT_STRIDE], 1);
                    if (g < (k + 1) * segcap) recs[g] = rec;
                    else {
                        int oi = atomicAdd(&flags[8], 1);
                        if (oi < OVF_MAX) { ovf[2 * oi] = r; ovf[2 * oi + 1] = c; }
                    }
                }
            }
        }
        __syncthreads();
        bool last = (rd == nround - 1);
        for (int k = wid; k < nbkt; k += nw) {
            int cnt = lcnt[k]; if (cnt > SLOTS) cnt = SLOTS;
            if (cnt >= FLUSH_T || (last && cnt > 0)) {
                int g = 0;
                if (lane == 0) g = atomicAdd(&gtail[k * GT_STRIDE], cnt);
                g = __shfl(g, 0);
                if (lane < cnt) {
                    int gg = g + lane;
                    unsigned int rec = lstage[k * SLOTS + lane];
                    if (gg < (k + 1) * segcap) recs[gg] = rec;
                    else {
                        int oi = atomicAdd(&flags[8], 1);
                        if (oi < OVF_MAX) {
                            ovf[2 * oi] = (k << 8) | (int)(rec >> 17);
                            ovf[2 * oi + 1] = (int)(rec & 0x1FFFF);
                        }
                    }
                }
                if (lane == 0) lcnt[k] = 0;
            }
        }
        __syncthreads();
    }
    for (int off = 32; off > 0; off >>= 1) mnr = min(mnr, __shfl_down(mnr, off, 64));
    if (lane == 0) sred[wid] = mnr;
    __syncthreads();
    if (tid == 0) {
        int m = 0x7fffffff;
        for (int i = 0; i < 16; ++i) m = min(m, sred[i]);
        atomicMin(&flags[1], m);
    }
}

// Two sub-blocks per bucket, each owning 128 rows (512 thr, 32.5KB LDS ->
// 4 blocks/CU, 32 waves/CU). Phase 1: bin this half's records into per-row
// LDS lists; pad odd rows with sentinel col N (zero Wtb row). Phase 2: wave
// per row; Wtb read as uint (channels 2l/2l+1 in lane l of each 32-lane
// half; halves take even/odd records) => half the loads + addr math of the
// R11 ushort scheme; col indices via ds_read_b128. shfl_xor(32) merges the
// two halves once per row.
__global__ __launch_bounds__(512, 8) void LINK_bgather_kernel(
    const int* __restrict__ gtail, const unsigned int* __restrict__ recs, int segcap,
    const unsigned short* __restrict__ Wtb, const float* __restrict__ bias,
    float* __restrict__ out, int* __restrict__ flags, int* __restrict__ ovf, int N) {
    __shared__ __attribute__((aligned(16))) int lcols[128 * SL];  // 32 KB
    __shared__ int lcnt[128];
    int b = blockIdx.x >> 1;
    int sub = blockIdx.x & 1;
    int tid = threadIdx.x;
    if (tid < 128) lcnt[tid] = 0;
    __syncthreads();
    int len = gtail[b * GT_STRIDE] - b * segcap;
    if (len > segcap) len = segcap;
    if (len < 0) len = 0;
    const unsigned int* rp = recs + (size_t)b * segcap;
    for (int i = tid; i < len; i += 512) {
        unsigned int rec = rp[i];
        int lrf = (int)(rec >> 17);
        if ((lrf >> 7) != sub) continue;
        int lr = lrf & 127;
        int c = (int)(rec & 0x1FFFF);
        int pos = atomicAdd(&lcnt[lr], 1);
        if (pos < SL) {
            lcols[(lr << 6) + pos] = c;
        } else {  // astronomically rare: defer to global ovf cleanup (raw row)
            int oi = atomicAdd(&flags[8], 1);
            if (oi < OVF_MAX) { ovf[2 * oi] = (b << 8) | lrf; ovf[2 * oi + 1] = c; }
        }
    }
    __syncthreads();
    // Pad odd-count rows to even with sentinel col N (Wtb row N == 0).
    if (tid < 128) {
        int c0 = lcnt[tid]; if (c0 > SL) c0 = SL;
        if (c0 & 1) { lcols[(tid << 6) + c0] = N; ++c0; }
        lcnt[tid] = c0;
    }
    __syncthreads();
    int rmin = flags[1];
    int lane = tid & 63, wid = tid >> 6;  // 8 waves
    int half = lane >> 5, ln = lane & 31;
    const unsigned int* __restrict__ W32 = (const unsigned int*)Wtb;
    float bv = bias[(ln << 1) + half];
    for (int lr = wid; lr < 128; lr += 8) {
        int cnt = lcnt[lr];         // even, <= SL
        int base = lr << 6;
        float aL = 0.0f, aH = 0.0f;
        int j = 0;
        for (; j + 16 <= cnt; j += 16) {   // 16 records: 8 dword loads/lane-half
            int4 q0 = *(const int4*)&lcols[base + j + (half << 2)];
            int4 q1 = *(const int4*)&lcols[base + j + 8 + (half << 2)];
            unsigned int u0 = W32[(((unsigned)q0.x) << 5) | ln];
            unsigned int u1 = W32[(((unsigned)q0.y) << 5) | ln];
            unsigned int u2 = W32[(((unsigned)q0.z) << 5) | ln];
            unsigned int u3 = W32[(((unsigned)q0.w) << 5) | ln];
            unsigned int u4 = W32[(((unsigned)q1.x) << 5) | ln];
            unsigned int u5 = W32[(((unsigned)q1.y) << 5) | ln];
            unsigned int u6 = W32[(((unsigned)q1.z) << 5) | ln];
            unsigned int u7 = W32[(((unsigned)q1.w) << 5) | ln];
            float l0 = (bflo(u0) + bflo(u1)) + (bflo(u2) + bflo(u3));
            float l1 = (bflo(u4) + bflo(u5)) + (bflo(u6) + bflo(u7));
            float h0 = (bfhi(u0) + bfhi(u1)) + (bfhi(u2) + bfhi(u3));
            float h1 = (bfhi(u4) + bfhi(u5)) + (bfhi(u6) + bfhi(u7));
            aL += l0 + l1;
            aH += h0 + h1;
        }
        for (; j + 8 <= cnt; j += 8) {     // 8 records: 4 dword loads/lane-half
            int4 q = *(const int4*)&lcols[base + j + (half << 2)];
            unsigned int u0 = W32[(((unsigned)q.x) << 5) | ln];
            unsigned int u1 = W32[(((unsigned)q.y) << 5) | ln];
            unsigned int u2 = W32[(((unsigned)q.z) << 5) | ln];
            unsigned int u3 = W32[(((unsigned)q.w) << 5) | ln];
            aL += (bflo(u0) + bflo(u1)) + (bflo(u2) + bflo(u3));
            aH += (bfhi(u0) + bfhi(u1)) + (bfhi(u2) + bfhi(u3));
        }
        for (; j + 4 <= cnt; j += 4) {     // 4 records: 2 dword loads/lane-half
            int2 q = *(const int2*)&lcols[base + j + (half << 1)];
            unsigned int u0 = W32[(((unsigned)q.x) << 5) | ln];
            unsigned int u1 = W32[(((unsigned)q.y) << 5) | ln];
            aL += bflo(u0) + bflo(u1);
            aH += bfhi(u0) + bfhi(u1);
        }
        for (; j + 2 <= cnt; j += 2) {     // 2 records: 1 dword load/lane-half
            int c = lcols[base + j + half];
            unsigned int u = W32[(((unsigned)c) << 5) | ln];
            aL += bflo(u);
            aH += bfhi(u);
        }
        aL += __shfl_xor(aL, 32, 64);
        aH += __shfl_xor(aH, 32, 64);
        int orow = (b << 8) + (sub << 7) + lr - rmin;
        if ((unsigned)orow < (unsigned)N)
            out[((size_t)orow << 6) + (ln << 1) + half] = (half ? aH : aL) + bv;
    }
}

// Bias for out rows not covered by any bucket (only when rmin large; usually no-op).
__global__ void LINK_biastail_kernel(float* __restrict__ out, const float* __restrict__ bias,
                                     const int* __restrict__ flags, int N, int nbkt) {
    int rmin = flags[1];
    long long start = (long long)nbkt * 256 - (long long)rmin;
    if (start < 0) start = 0;
    if (start >= N) return;
    long long total = ((long long)N - start) * 64;
    long long base = start * 64;
    long long i0 = (long long)blockIdx.x * blockDim.x + threadIdx.x;
    long long stride = (long long)gridDim.x * blockDim.x;
    for (long long i = i0; i < total; i += stride) out[base + i] = bias[(int)(i & 63)];
}

// Cleanup for spilled edges (expected zero on real data). ovf[2i] = raw row.
__global__ void LINK_ovf_kernel(const int* __restrict__ ovf, const int* __restrict__ flags,
                                const unsigned short* __restrict__ Wtb,
                                float* __restrict__ out, int N) {
    int g = blockIdx.x * blockDim.x + threadIdx.x;
    int w = g >> 6, lane = g & 63;
    int cnt = flags[8]; if (cnt > OVF_MAX) cnt = OVF_MAX;
    if (cnt == 0) return;
    int rmin = flags[1];
    int nw = (gridDim.x * blockDim.x) >> 6;
    for (int i = w; i < cnt; i += nw) {
        int r = ovf[2 * i] - rmin;
        int c = ovf[2 * i + 1];
        if ((unsigned)r >= (unsigned)N || (unsigned)c >= (unsigned)N) continue;
        atomicAdd(&out[((size_t)r << 6) + lane], bf16u_to_f(Wtb[((size_t)c << 6) + lane]));
    }
}

// ---- Fallback path for unexpected shapes/ws: analyze + bias init + scatter ----
__global__ void LINK_initout_kernel(float* __restrict__ out, const float* __restrict__ b,
                                    int total, int* __restrict__ flags) {
    int i = blockIdx.x * blockDim.x + threadIdx.x;
    if (i == 0) { flags[0] = 0; flags[1] = 0x7fffffff; flags[2] = 0x7fffffff; }
    if (i < total) out[i] = b[i & 63];
}

__global__ __launch_bounds__(256) void LINK_analyze_kernel(
    const unsigned int* __restrict__ words, int E, int* __restrict__ flags) {
    const uint4* __restrict__ w4 = (const uint4*)words;
    int tid = blockIdx.x * blockDim.x + threadIdx.x;
    int nth = gridDim.x * blockDim.x;
    int n1 = E >> 2;
    long long twoE = 2LL * E;
    int n2 = (int)(twoE >> 2);
    unsigned int oddOr = 0u;
    int mn32 = 0x7fffffff, mn64 = 0x7fffffff;
    for (int i = tid; i < n2; i += nth) {
        uint4 w = w4[i];
        oddOr |= (w.y | w.w);
        mn64 = min(mn64, min((int)w.x, (int)w.z));
        if (i < n1)
            mn32 = min(mn32, min(min((int)w.x, (int)w.y), min((int)w.z, (int)w.w)));
    }
    for (long long i = ((long long)n1 << 2) + tid; i < E; i += nth)
        mn32 = min(mn32, (int)words[i]);
    for (long long i = ((long long)n2 << 2) + tid; i < twoE; i += nth) {
        unsigned int w = words[i];
        if (i & 1) oddOr |= w; else mn64 = min(mn64, (int)w);
    }
    for (int off = 32; off > 0; off >>= 1) {
        oddOr |= (unsigned int)__shfl_down((int)oddOr, off, 64);
        mn32 = min(mn32, __shfl_down(mn32, off, 64));
        mn64 = min(mn64, __shfl_down(mn64, off, 64));
    }
    __shared__ int s_or[4], s_m32[4], s_m64[4];
    int wid = threadIdx.x >> 6;
    if ((threadIdx.x & 63) == 0) { s_or[wid] = (int)oddOr; s_m32[wid] = mn32; s_m64[wid] = mn64; }
    __syncthreads();
    if (threadIdx.x == 0) {
        int o = s_or[0] | s_or[1] | s_or[2] | s_or[3];
        int a = min(min(s_m32[0], s_m32[1]), min(s_m32[2], s_m32[3]));
        int d = min(min(s_m64[0], s_m64[1]), min(s_m64[2], s_m64[3]));
        if (o) atomicOr(&flags[0], 1);
        atomicMin(&flags[1], a);
        atomicMin(&flags[2], d);
    }
}

__global__ void LINK_scatter_kernel(const unsigned int* __restrict__ words, int E,
                                    const float* __restrict__ W,
                                    float* __restrict__ out,
                                    const int* __restrict__ flags, int N) {
    long long g = (long long)blockIdx.x * blockDim.x + threadIdx.x;
    int e = (int)(g >> 6);
    if (e >= E) return;
    int ch = (int)(g & 63);
    int r, c, rmin;
    if (flags[0]) { r = (int)words[e]; c = (int)words[E + e]; rmin = flags[1]; }
    else { r = (int)words[2LL * e]; c = (int)words[2LL * (E + e)]; rmin = flags[2]; }
    r -= rmin;
    if ((unsigned)r >= (unsigned)N || (unsigned)c >= (unsigned)N) return;
    atomicAdd(&out[((size_t)r << 6) + ch], W[(size_t)ch * N + c]);
}

static inline size_t align256(size_t x) { return (x + 255) & ~(size_t)255; }

extern "C" void kernel_launch(void* const* d_in, const int* in_sizes, int n_in,
                              void* d_out, int out_size, void* d_ws, size_t ws_size,
                              hipStream_t stream) {
    const unsigned int* words = (const unsigned int*)d_in[0];
    const float* W = (const float*)d_in[1];
    const float* b = (const float*)d_in[2];
    float* out = (float*)d_out;

    int E = in_sizes[0] / 2;   // 3,200,000
    int N = in_sizes[1] / 64;  // 100,000
    int total = out_size;      // N*64
    int nbkt = (N + 255) / 256;  // 391

    size_t off_flags = 0;
    size_t off_wtb   = align256(off_flags + 256 * sizeof(int));
    size_t off_gtail = align256(off_wtb + (size_t)(N + 1) * 64 * sizeof(unsigned short));
    size_t off_ovf   = align256(off_gtail + (size_t)NBKT_MAX * GT_STRIDE * sizeof(int));
    size_t off_recs  = align256(off_ovf + (size_t)OVF_MAX * 2 * sizeof(int));

    int* flags = (int*)((char*)d_ws + off_flags);
    unsigned short* Wtb = (unsigned short*)((char*)d_ws + off_wtb);
    int* gtail = (int*)((char*)d_ws + off_gtail);
    int* ovf   = (int*)((char*)d_ws + off_ovf);
    unsigned int* recs = (unsigned int*)((char*)d_ws + off_recs);

    long long avail = (ws_size > off_recs)
        ? (long long)((ws_size - off_recs) / ((size_t)nbkt * sizeof(int))) : 0;
    int segcap = (int)(avail > 16384 ? 16384 : avail);
    int avg = (int)((long long)E / (nbkt > 0 ? nbkt : 1)) + 1;
    bool useMain = (N <= (1 << 17)) && (nbkt <= NBKT_MAX) &&
                   (segcap >= avg + avg / 4 + SLOTS) && (E > 0);

    if (useMain) {
        LINK_detect_kernel<<<1, 1024, 0, stream>>>(words, E, flags, gtail, nbkt, segcap);
        LINK_transpose_kernel<<<(N + 64) / 64, 256, 0, stream>>>(W, Wtb, N);
        LINK_part_kernel<<<512, 1024, 0, stream>>>(words, E, N, nbkt, segcap,
                                                   gtail, recs, ovf, flags);
        LINK_bgather_kernel<<<nbkt * 2, 512, 0, stream>>>(gtail, recs, segcap, Wtb, b,
                                                          out, flags, ovf, N);
        LINK_biastail_kernel<<<64, 256, 0, stream>>>(out, b, flags, N, nbkt);
        LINK_ovf_kernel<<<64, 256, 0, stream>>>(ovf, flags, Wtb, out, N);
    } else {
        LINK_initout_kernel<<<(total + 255) / 256, 256, 0, stream>>>(out, b, total, flags);
        LINK_analyze_kernel<<<256, 256, 0, stream>>>(words, E, flags);
        long long tthreads = (long long)E * 64;
        LINK_scatter_kernel<<<(int)((tthreads + 255) / 256), 256, 0, stream>>>(
            words, E, W, out, flags, N);
    }
}